// Round 7
// baseline (79.489 us; speedup 1.0000x reference)
//
#include <hip/hip_runtime.h>

// Depth-4 path signature, B=128, L=128, C=12, fp32.
// Round 12: five loop rewrites (R1/R2/R4/R5/R6) all land 73-78us ->
// the 32-iter loop is ~7-8us issue-bound of the 20us kernel, not 15.
// Remaining loop residual is latency-hiding at 1.75 waves/SIMD.
// Fix: IN-BLOCK TIME SPLIT via Chen associativity. 896-thread block:
// waves 0-6 compute sig(steps 0..63), waves 7-13 compute sig(64..127)
// (wave-uniform split, no divergence). Same aggregate VALU, half the
// serial loop length, 14 waves/CU (3.5/SIMD) -> 2x latency hiding.
// B-waves also track mirrored-i level<=3 state (+8 ops/substep) so the
// block holds FULL-index B1/B2/B3 for the combine; B4 needed only at
// own (i,j,k,l). Partials -> LDS, one barrier, A-threads apply
// C_m = A_m + B_m + sum A_i (x) B_{m-i} and store. No workspace.

#define NC    12
#define NPTS  128
#define OUT_PER_B 22620      // 12 + 144 + 1728 + 20736
#define BT    896            // 2 time-groups x 448 (432 active each)
#define PADQ  33             // float4 row stride in transposed LDS table
#define SB4S  25             // padded row stride of SB4 (bank-conflict-free)

__global__ __launch_bounds__(BT)
void sig_kernel(const float* __restrict__ path, float* __restrict__ out) {
    const int bid = blockIdx.x;
    const int b  = bid >> 1;
    const int ih = bid & 1;
    const int t  = threadIdx.x;

    __shared__ __align__(16) float  P[NPTS * NC];     // 6144 B staged path
    __shared__ __align__(16) float  W[NPTS * NC];     // 6144 B row-major [s][c]
    __shared__ __align__(16) float4 DT4[NC * PADQ];   // 6336 B transposed [c][sq]
    __shared__ float SB1[12];                         // B-half level 1
    __shared__ float SB2[144];                        // B-half level 2
    __shared__ float SB3[1728];                       // B-half level 3
    __shared__ float SB4[432 * SB4S];                 // B-half level 4 (43.2 KB)

    // ---- stage path, coalesced ----
    const float* pb = path + (size_t)b * (NPTS * NC);
    if (t < 384) ((float4*)P)[t] = ((const float4*)pb)[t];
    __syncthreads();

    // ---- increments into both LDS layouts (one-time) ----
    if (t < 384) {
        const int c  = t >> 5;        // 0..11
        const int sq = t & 31;        // 0..31
        float d[4];
        #pragma unroll
        for (int e = 0; e < 4; ++e) {
            const int s = 4 * sq + e;
            d[e] = (s < NPTS - 1) ? (P[(s + 1) * NC + c] - P[s * NC + c]) : 0.f;
            W[s * NC + c] = d[e];
        }
        DT4[c * PADQ + sq] = make_float4(d[0], d[1], d[2], d[3]);
    }
    __syncthreads();

    // ---- index map; g = time-half (wave-uniform: 448 = 7 waves) ----
    const int g  = (t >= 448) ? 1 : 0;
    const int tt = t - (g ? 448 : 0);          // 0..447 within group
    const int ta  = (tt < 432) ? tt : (tt - 432);
    const int il  = ta / 72;
    const int rem = ta - il * 72;
    const int j   = rem / 6;
    const int kh  = rem - j * 6;
    const int i   = ih * 6 + il;               // own i (this block's half)
    const int ip  = (1 - ih) * 6 + il;         // mirrored i (other half)
    const int k0  = kh * 2;

    float acc0[12], acc1[12];
    #pragma unroll
    for (int l = 0; l < 12; ++l) { acc0[l] = 0.f; acc1[l] = 0.f; }
    float s1 = 0.f, s2 = 0.f, s3a = 0.f, s3b = 0.f;          // own chain
    float s1p = 0.f, s2p = 0.f, s3pa = 0.f, s3pb = 0.f;      // mirrored (B only)

    const float4* wt   = (const float4*)W;
    const float4* dti  = &DT4[i * PADQ];
    const float4* dtj  = &DT4[j * PADQ];
    const float4* dtka = &DT4[k0 * PADQ];
    const float4* dtkb = &DT4[(k0 + 1) * PADQ];
    const float4* dtip = &DT4[ip * PADQ];

#define LOAD_COMMON(S)                                                \
    float4 wq[12];                                                    \
    _Pragma("unroll")                                                 \
    for (int qq = 0; qq < 12; ++qq) wq[qq] = wt[(S) * 12 + qq];       \
    float4 di4 = dti[S], dj4 = dtj[S], dka4 = dtka[S], dkb4 = dtkb[S];

#define CHEN_U(u) do {                                                \
        const float di  = (&di4.x)[u];                                \
        const float dj  = (&dj4.x)[u];                                \
        const float dka = (&dka4.x)[u];                               \
        const float dkb = (&dkb4.x)[u];                               \
        float A4  = (s1 + 0.25f * di) * (1.f / 3.f);                  \
        float B4  = (s2 + dj * A4) * 0.5f;                            \
        float C3a_ = s3a + dka * B4;                                  \
        float C3b_ = s3b + dkb * B4;                                  \
        _Pragma("unroll")                                             \
        for (int l = 0; l < 12; ++l) {                                \
            const float wl = (&wq[3 * u + (l >> 2)].x)[l & 3];        \
            acc0[l] += C3a_ * wl;                                     \
            acc1[l] += C3b_ * wl;                                     \
        }                                                             \
        float A3 = (s1 + di * (1.f / 3.f)) * 0.5f;                    \
        float C2 = s2 + dj * A3;                                      \
        s3a += dka * C2;                                              \
        s3b += dkb * C2;                                              \
        s2  += dj * (s1 + 0.5f * di);                                 \
        s1  += di;                                                    \
    } while (0)

#define CHEN_UP(u) do {                                               \
        const float dip = (&dip4.x)[u];                               \
        const float dj  = (&dj4.x)[u];                                \
        const float dka = (&dka4.x)[u];                               \
        const float dkb = (&dkb4.x)[u];                               \
        float A3p = (s1p + dip * (1.f / 3.f)) * 0.5f;                 \
        float C2p = s2p + dj * A3p;                                   \
        s3pa += dka * C2p;                                            \
        s3pb += dkb * C2p;                                            \
        s2p  += dj * (s1p + 0.5f * dip);                              \
        s1p  += dip;                                                  \
    } while (0)

    if (!g) {
        // ---- time-half A: steps 0..63 (sq 0..15) ----
        for (int q = 0; q < 16; ++q) {
            LOAD_COMMON(q);
            #pragma unroll
            for (int u = 0; u < 4; ++u) CHEN_U(u);
        }
    } else {
        // ---- time-half B: steps 64..127 (sq 16..31; step 127 = pad) ----
        for (int q = 16; q < 32; ++q) {
            LOAD_COMMON(q);
            float4 dip4 = dtip[q];
            #pragma unroll
            for (int u = 0; u < 4; ++u) { CHEN_U(u); CHEN_UP(u); }
        }
        // stash B partials (guarded: pad threads excluded)
        if (tt < 432) {
            #pragma unroll
            for (int l = 0; l < 12; ++l) {
                SB4[tt * SB4S + l]      = acc0[l];
                SB4[tt * SB4S + 12 + l] = acc1[l];
            }
            SB3[i  * 144 + j * 12 + k0]     = s3a;
            SB3[i  * 144 + j * 12 + k0 + 1] = s3b;
            SB3[ip * 144 + j * 12 + k0]     = s3pa;
            SB3[ip * 144 + j * 12 + k0 + 1] = s3pb;
            if (kh == 0) { SB2[i * 12 + j] = s2; SB2[ip * 12 + j] = s2p; }
            if (j == 0 && kh == 0) { SB1[i] = s1; SB1[ip] = s1p; }
        }
    }
    __syncthreads();

    // ---- Chen combine C = A (x) B, done by A-threads; store ----
    if (!g && tt < 432) {
        float* ob = out + (size_t)b * OUT_PER_B;
        if (j == 0 && kh == 0) ob[i] = s1 + SB1[i];                    // lvl 1
        if (kh == 0)
            ob[12 + i * 12 + j] = s2 + SB2[i * 12 + j] + s1 * SB1[j];  // lvl 2
        const int ijk = (i * 12 + j) * 12 + k0;
        ob[156 + ijk] = s3a + SB3[i * 144 + j * 12 + k0]               // lvl 3
                      + s1 * SB2[j * 12 + k0] + s2 * SB1[k0];
        ob[156 + ijk + 1] = s3b + SB3[i * 144 + j * 12 + k0 + 1]
                      + s1 * SB2[j * 12 + k0 + 1] + s2 * SB1[k0 + 1];
        float c4[24];
        #pragma unroll
        for (int l = 0; l < 12; ++l) {                                 // lvl 4
            c4[l] = acc0[l] + SB4[tt * SB4S + l]
                  + s1 * SB3[j * 144 + k0 * 12 + l]
                  + s2 * SB2[k0 * 12 + l]
                  + s3a * SB1[l];
            c4[12 + l] = acc1[l] + SB4[tt * SB4S + 12 + l]
                  + s1 * SB3[j * 144 + (k0 + 1) * 12 + l]
                  + s2 * SB2[(k0 + 1) * 12 + l]
                  + s3b * SB1[l];
        }
        float4* o4 = (float4*)(ob + 1884 + (size_t)ijk * 12);          // 96 B
        o4[0] = make_float4(c4[0],  c4[1],  c4[2],  c4[3]);
        o4[1] = make_float4(c4[4],  c4[5],  c4[6],  c4[7]);
        o4[2] = make_float4(c4[8],  c4[9],  c4[10], c4[11]);
        o4[3] = make_float4(c4[12], c4[13], c4[14], c4[15]);
        o4[4] = make_float4(c4[16], c4[17], c4[18], c4[19]);
        o4[5] = make_float4(c4[20], c4[21], c4[22], c4[23]);
    }

#undef LOAD_COMMON
#undef CHEN_U
#undef CHEN_UP
}

extern "C" void kernel_launch(void* const* d_in, const int* in_sizes, int n_in,
                              void* d_out, int out_size, void* d_ws, size_t ws_size,
                              hipStream_t stream) {
    const float* path = (const float*)d_in[0];
    float* out = (float*)d_out;
    const int nbatch = in_sizes[0] / (NPTS * NC);   // = 128

    sig_kernel<<<nbatch * 2, BT, 0, stream>>>(path, out);
}

// Round 8
// 73.692 us; speedup vs baseline: 1.0787x; 1.0787x over previous
//
#include <hip/hip_runtime.h>

// Depth-4 path signature, B=128, L=128, C=12, fp32.
// Round 13: REVERT to the best-measured variant (round-6/"R1" fused
// kernel, 73.25us, absmax 1.0). Six structural rewrites (LDS-traffic /3,
// occupancy x2 and /2, serial-length /2, reg double-buffer, scalar-pipe
// broadcast, in-block Chen time-split) all landed 73-79.5us -> the ~20us
// kernel (measured via R8's double-launch delta) is dominated by
// launch/ramp/stage/drain terms insensitive to loop structure; the
// remaining ~53us of the timed region is the harness's 256MiB poison
// fill (~42us at 6.5TB/s, visible in every rocprof top-5) plus the
// reset dispatch train. This source is byte-identical in behavior to
// the 73.25us round-1 measurement.

#define NC    12
#define NPTS  128
#define NSTEP 128            // 127 real increments + 1 zero pad (identity)
#define OUT_PER_B 22620      // 12 + 144 + 1728 + 20736
#define BT 448               // 432 active = 6(i) * 12(j) * 6(k-pairs)
#define PADQ 33              // float4 row stride in transposed LDS table

__global__ __launch_bounds__(BT)
void sig_kernel(const float* __restrict__ path, float* __restrict__ out) {
    const int bid = blockIdx.x;
    const int b  = bid >> 1;
    const int ih = bid & 1;
    const int t  = threadIdx.x;

    __shared__ __align__(16) float  P[NPTS * NC];     // 6144 B staged path
    __shared__ __align__(16) float  W[NSTEP * NC];    // 6144 B row-major [s][c]
    __shared__ __align__(16) float4 DT4[NC * PADQ];   // 6336 B transposed [c][sq]

    // ---- stage path, coalesced (384 float4 = 6 KB) ----
    const float* pb = path + (size_t)b * (NPTS * NC);
    if (t < 384) ((float4*)P)[t] = ((const float4*)pb)[t];
    __syncthreads();

    // ---- increments into both LDS layouts (one-time) ----
    if (t < 384) {
        const int c  = t >> 5;        // 0..11
        const int sq = t & 31;        // 0..31
        float d[4];
        #pragma unroll
        for (int e = 0; e < 4; ++e) {
            const int s = 4 * sq + e;
            d[e] = (s < NPTS - 1) ? (P[(s + 1) * NC + c] - P[s * NC + c]) : 0.f;
            W[s * NC + c] = d[e];
        }
        DT4[c * PADQ + sq] = make_float4(d[0], d[1], d[2], d[3]);
    }
    __syncthreads();

    // ---- index map (pad threads duplicate work; stores guarded later) ----
    const int ta  = (t < 432) ? t : (t - 432);
    const int il  = ta / 72;
    const int rem = ta - il * 72;
    const int j   = rem / 6;
    const int kh  = rem - j * 6;
    const int i   = ih * 6 + il;
    const int k0  = kh * 2;

    float acc0[12], acc1[12];
    #pragma unroll
    for (int l = 0; l < 12; ++l) { acc0[l] = 0.f; acc1[l] = 0.f; }
    float s3a = 0.f, s3b = 0.f, s2 = 0.f, s1 = 0.f;

    const float4* wt   = (const float4*)W;        // 12 float4 per sq group
    const float4* dti  = &DT4[i * PADQ];
    const float4* dtj  = &DT4[j * PADQ];
    const float4* dtka = &DT4[k0 * PADQ];
    const float4* dtkb = &DT4[(k0 + 1) * PADQ];

    for (int sq = 0; sq < NSTEP / 4; ++sq) {
        // block-uniform 48 increments for these 4 steps: LDS broadcast reads
        float4 wq[12];
        #pragma unroll
        for (int q = 0; q < 12; ++q) wq[q] = wt[sq * 12 + q];

        // per-thread transposed reads (<=2-way conflict = free)
        float4 di4  = dti[sq];
        float4 dj4  = dtj[sq];
        float4 dka4 = dtka[sq];
        float4 dkb4 = dtkb[sq];

        #pragma unroll
        for (int u = 0; u < 4; ++u) {
            const float di  = (&di4.x)[u];
            const float dj  = (&dj4.x)[u];
            const float dka = (&dka4.x)[u];
            const float dkb = (&dkb4.x)[u];

            // Horner-factored Chen step
            float A4  = (s1 + 0.25f * di) * (1.f / 3.f);
            float B4  = (s2 + dj * A4) * 0.5f;
            float C3a = s3a + dka * B4;
            float C3b = s3b + dkb * B4;

            #pragma unroll
            for (int l = 0; l < 12; ++l) {
                const float wl = (&wq[3 * u + (l >> 2)].x)[l & 3];
                acc0[l] += C3a * wl;
                acc1[l] += C3b * wl;
            }

            float A3 = (s1 + di * (1.f / 3.f)) * 0.5f;
            float C2 = s2 + dj * A3;
            s3a += dka * C2;
            s3b += dkb * C2;
            s2  += dj * (s1 + 0.5f * di);
            s1  += di;
        }
    }

    if (t < 432) {
        float* ob = out + (size_t)b * OUT_PER_B;
        if (j == 0 && kh == 0) ob[i] = s1;                 // level 1
        if (kh == 0) ob[12 + i * 12 + j] = s2;             // level 2
        const int ijk = (i * 12 + j) * 12 + k0;
        ob[156 + ijk]     = s3a;                           // level 3
        ob[156 + ijk + 1] = s3b;
        float4* o4 = (float4*)(ob + 1884 + (size_t)ijk * 12);  // level 4, 96B
        o4[0] = make_float4(acc0[0], acc0[1], acc0[2],  acc0[3]);
        o4[1] = make_float4(acc0[4], acc0[5], acc0[6],  acc0[7]);
        o4[2] = make_float4(acc0[8], acc0[9], acc0[10], acc0[11]);
        o4[3] = make_float4(acc1[0], acc1[1], acc1[2],  acc1[3]);
        o4[4] = make_float4(acc1[4], acc1[5], acc1[6],  acc1[7]);
        o4[5] = make_float4(acc1[8], acc1[9], acc1[10], acc1[11]);
    }
}

extern "C" void kernel_launch(void* const* d_in, const int* in_sizes, int n_in,
                              void* d_out, int out_size, void* d_ws, size_t ws_size,
                              hipStream_t stream) {
    const float* path = (const float*)d_in[0];
    float* out = (float*)d_out;
    const int nbatch = in_sizes[0] / (NPTS * NC);   // = 128

    sig_kernel<<<nbatch * 2, BT, 0, stream>>>(path, out);
}